// Round 1
// baseline (692.217 us; speedup 1.0000x reference)
//
#include <hip/hip_runtime.h>
#include <math.h>

#define NF 8
#define NH 200
#define NC 8
#define BT 64      // batch elements per block (== lanes per wave)
#define NWAVE 8    // waves per block
#define JB 25      // hidden units owned per wave (8*25 = 200)
#define CH 8       // k-chunk for the 200-wide dot products

// ---------------------------------------------------------------------------
// Prep: invert Q (8x8) via Gauss-Jordan with partial pivoting. 128 threads,
// thread (r, c2) owns augmented element aug[r][c2], [Q | I] -> [I | Q^-1].
// For Q == identity this is exact (pivots are 1.0, eliminations are no-ops).
// ---------------------------------------------------------------------------
__global__ void qinv_kernel(const float* __restrict__ Q, float* __restrict__ Qi)
{
    __shared__ float aug[8][16];
    __shared__ int piv;
    const int t  = threadIdx.x;   // 0..127
    const int r  = t >> 4;        // 0..7
    const int c2 = t & 15;        // 0..15
    aug[r][c2] = (c2 < 8) ? Q[r * 8 + c2] : ((c2 - 8 == r) ? 1.0f : 0.0f);
    __syncthreads();

    for (int c = 0; c < 8; ++c) {
        if (t == 0) {
            int p = c; float best = fabsf(aug[c][c]);
            for (int rr = c + 1; rr < 8; ++rr) {
                float v = fabsf(aug[rr][c]);
                if (v > best) { best = v; p = rr; }
            }
            piv = p;
        }
        __syncthreads();
        const int p = piv;
        // swap rows c and p (no-op if p == c)
        float myv = aug[r][c2];
        __syncthreads();
        if (r == c)      aug[p][c2] = myv;
        else if (r == p) aug[c][c2] = myv;
        __syncthreads();
        // scale pivot row
        const float pv = aug[c][c];
        __syncthreads();
        if (r == c) aug[r][c2] = aug[r][c2] / pv;
        __syncthreads();
        // eliminate
        const float fac  = (r == c) ? 0.0f : aug[r][c];
        const float prow = aug[c][c2];
        __syncthreads();
        aug[r][c2] -= fac * prow;
        __syncthreads();
    }
    if (c2 >= 8) Qi[r * 8 + (c2 - 8)] = aug[r][c2];
}

// ---------------------------------------------------------------------------
// One 200x200 (+bias, ReLU) layer. Activations live transposed in LDS:
// act[j*BT + lane] -> lane-consecutive addresses, conflict-free.
// Weights are read at wave-uniform addresses (j0 is SGPR) -> s_load.
// ---------------------------------------------------------------------------
__device__ __forceinline__ void layer200(const float* __restrict__ in_,
                                         float* __restrict__ out_,
                                         const float* __restrict__ W,
                                         const float* __restrict__ bias,
                                         int j0, int lane)
{
    float acc[JB];
#pragma unroll
    for (int jj = 0; jj < JB; ++jj) acc[jj] = bias[j0 + jj];
#pragma unroll 1
    for (int k0 = 0; k0 < NH; k0 += CH) {
        float a[CH];
#pragma unroll
        for (int u = 0; u < CH; ++u) a[u] = in_[(k0 + u) * BT + lane];
#pragma unroll
        for (int jj = 0; jj < JB; ++jj) {
            const float* wr = W + (j0 + jj) * NH + k0;   // uniform address
#pragma unroll
            for (int u = 0; u < CH; ++u) acc[jj] = fmaf(wr[u], a[u], acc[jj]);
        }
    }
#pragma unroll
    for (int jj = 0; jj < JB; ++jj)
        out_[(j0 + jj) * BT + lane] = fmaxf(acc[jj], 0.0f);
}

__global__ __launch_bounds__(BT * NWAVE, 2)
void mlp_fused(const float* __restrict__ x, const float* __restrict__ Qi,
               const float* __restrict__ W0, const float* __restrict__ b0,
               const float* __restrict__ W1, const float* __restrict__ b1,
               const float* __restrict__ W2, const float* __restrict__ b2,
               const float* __restrict__ W3, const float* __restrict__ b3,
               const float* __restrict__ W4, const float* __restrict__ b4,
               float* __restrict__ out, int B)
{
    __shared__ float actA[NH * BT];                  // 51.2 KB
    __shared__ float actB[NH * BT];                  // 51.2 KB
    __shared__ float outP[NWAVE * NC * BT];          // 16.0 KB

    const int lane = threadIdx.x & 63;
    const int wid  = __builtin_amdgcn_readfirstlane((int)(threadIdx.x >> 6));
    const int g    = blockIdx.x * BT + lane;         // batch element
    const int j0   = wid * JB;

    // ---- fc0: h = W0 x + b0 (each wave redundantly computes its lane's h) ----
    float xr[NF];
    if (g < B) {
        const float4* xp = reinterpret_cast<const float4*>(x + (size_t)g * NF);
        float4 x0 = xp[0], x1 = xp[1];
        xr[0] = x0.x; xr[1] = x0.y; xr[2] = x0.z; xr[3] = x0.w;
        xr[4] = x1.x; xr[5] = x1.y; xr[6] = x1.z; xr[7] = x1.w;
    } else {
#pragma unroll
        for (int i = 0; i < NF; ++i) xr[i] = 0.0f;
    }

    float h[NF];
#pragma unroll
    for (int j = 0; j < NF; ++j) {
        float acc = b0[j];
#pragma unroll
        for (int k = 0; k < NF; ++k) acc = fmaf(W0[j * NF + k], xr[k], acc);
        h[j] = acc;
    }

    // ---- QP layer, reduced KKT:  z = Qi h - Qi A' nu,
    //      nu = (A Qi A')^-1 (A Qi h - b),  b = A h  =>  exact z = h for Q = I.
    float tq[NF], u0[NF], u1[NF];
    const float h3 = h[3];
#pragma unroll
    for (int i = 0; i < NF; ++i) {
        float s = 0.0f;
#pragma unroll
        for (int k = 0; k < NF; ++k) s = fmaf(Qi[i * NF + k], h[k], s);
        tq[i] = s;
        u0[i] = fmaf(Qi[i * NF + 4], h3, Qi[i * NF + 5]);
        u1[i] = fmaf(Qi[i * NF + 6], h3, Qi[i * NF + 7]);
    }
    const float m00 = fmaf(h3, u0[4], u0[5]);
    const float m01 = fmaf(h3, u1[4], u1[5]);
    const float m10 = fmaf(h3, u0[6], u0[7]);
    const float m11 = fmaf(h3, u1[6], u1[7]);
    const float r0  = fmaf(h3, tq[4], tq[5]) - fmaf(h3, h[4], h[5]);
    const float r1  = fmaf(h3, tq[6], tq[7]) - fmaf(h3, h[6], h[7]);
    const float idet = 1.0f / (m00 * m11 - m01 * m10);
    const float nu0 = (m11 * r0 - m01 * r1) * idet;
    const float nu1 = (m00 * r1 - m10 * r0) * idet;
    float z[NF];
#pragma unroll
    for (int i = 0; i < NF; ++i) z[i] = tq[i] - u0[i] * nu0 - u1[i] * nu1;

    // ---- L1: 8 -> 200, ReLU, write transposed tile ----
#pragma unroll
    for (int jj = 0; jj < JB; ++jj) {
        const int j = j0 + jj;
        float acc = b1[j];
#pragma unroll
        for (int k = 0; k < NF; ++k) acc = fmaf(W1[j * NF + k], z[k], acc);
        actA[j * BT + lane] = fmaxf(acc, 0.0f);
    }
    __syncthreads();

    // ---- L2: 200 -> 200 ----
    layer200(actA, actB, W2, b2, j0, lane);
    __syncthreads();

    // ---- L3: 200 -> 200 ----
    layer200(actB, actA, W3, b3, j0, lane);
    __syncthreads();

    // ---- L4: 200 -> 8, k split across waves ----
    {
        float a[JB];
#pragma unroll
        for (int kk = 0; kk < JB; ++kk) a[kk] = actA[(j0 + kk) * BT + lane];
        float acc[NC];
#pragma unroll
        for (int o = 0; o < NC; ++o) acc[o] = 0.0f;
#pragma unroll
        for (int o = 0; o < NC; ++o) {
            const float* wr = W4 + o * NH + j0;      // uniform, contiguous
#pragma unroll
            for (int kk = 0; kk < JB; ++kk) acc[o] = fmaf(wr[kk], a[kk], acc[o]);
        }
#pragma unroll
        for (int o = 0; o < NC; ++o) outP[(wid * NC + o) * BT + lane] = acc[o];
    }
    __syncthreads();

    // ---- reduce partials: wave w handles output column o = wid ----
    {
        float s = b4[wid];
#pragma unroll
        for (int w = 0; w < NWAVE; ++w) s += outP[(w * NC + wid) * BT + lane];
        if (g < B) out[(size_t)g * NC + wid] = s;
    }
}

extern "C" void kernel_launch(void* const* d_in, const int* in_sizes, int n_in,
                              void* d_out, int out_size, void* d_ws, size_t ws_size,
                              hipStream_t stream)
{
    const float* x  = (const float*)d_in[0];
    const float* Q  = (const float*)d_in[1];
    const float* W0 = (const float*)d_in[2];
    const float* b0 = (const float*)d_in[3];
    const float* W1 = (const float*)d_in[4];
    const float* b1 = (const float*)d_in[5];
    const float* W2 = (const float*)d_in[6];
    const float* b2 = (const float*)d_in[7];
    const float* W3 = (const float*)d_in[8];
    const float* b3 = (const float*)d_in[9];
    const float* W4 = (const float*)d_in[10];
    const float* b4 = (const float*)d_in[11];
    float* out = (float*)d_out;
    float* Qi  = (float*)d_ws;   // 64 floats

    const int B = in_sizes[0] / NF;

    hipLaunchKernelGGL(qinv_kernel, dim3(1), dim3(128), 0, stream, Q, Qi);
    hipLaunchKernelGGL(mlp_fused, dim3((B + BT - 1) / BT), dim3(BT * NWAVE), 0, stream,
                       x, Qi, W0, b0, W1, b1, W2, b2, W3, b3, W4, b4, out, B);
}

// Round 2
// 94.501 us; speedup vs baseline: 7.3250x; 7.3250x over previous
//
#include <hip/hip_runtime.h>
#include <math.h>

typedef _Float16 f16;
typedef f16 half8 __attribute__((ext_vector_type(8)));
typedef float floatx4 __attribute__((ext_vector_type(4)));

#define NF 8
#define NH 200
#define NC 8

#define M_BLK 128
#define ACT_W 232          // halfs per act row: 224 data + 8 pad (464B stride -> 2-way banks)
#define NPAD 256
#define KPAD 224

// ---- d_ws byte layout (all 16B aligned) ----
#define WS_QI   0          // 64 f32
#define WS_B1P  256        // 256 f32 padded bias
#define WS_B2P  1280
#define WS_B3P  2304
#define WS_B4P  3328       // 16 f32
#define WS_W1H  3392       // f16 [256][32]
#define WS_W2H  19776      // f16 [256][224]
#define WS_W3H  134464     // f16 [256][224]
#define WS_W4H  249152     // f16 [16][224]
#define WS_NEED 256320

// ---------------------------------------------------------------------------
// Prep 1: invert Q (8x8) Gauss-Jordan w/ pivoting. Exact identity for Q=I.
// ---------------------------------------------------------------------------
__global__ void qinv_kernel(const float* __restrict__ Q, float* __restrict__ Qi)
{
    __shared__ float aug[8][16];
    __shared__ int piv;
    const int t  = threadIdx.x;
    const int r  = t >> 4;
    const int c2 = t & 15;
    aug[r][c2] = (c2 < 8) ? Q[r * 8 + c2] : ((c2 - 8 == r) ? 1.0f : 0.0f);
    __syncthreads();
    for (int c = 0; c < 8; ++c) {
        if (t == 0) {
            int p = c; float best = fabsf(aug[c][c]);
            for (int rr = c + 1; rr < 8; ++rr) {
                float v = fabsf(aug[rr][c]);
                if (v > best) { best = v; p = rr; }
            }
            piv = p;
        }
        __syncthreads();
        const int p = piv;
        float myv = aug[r][c2];
        __syncthreads();
        if (r == c)      aug[p][c2] = myv;
        else if (r == p) aug[c][c2] = myv;
        __syncthreads();
        const float pv = aug[c][c];
        __syncthreads();
        if (r == c) aug[r][c2] = aug[r][c2] / pv;
        __syncthreads();
        const float fac  = (r == c) ? 0.0f : aug[r][c];
        const float prow = aug[c][c2];
        __syncthreads();
        aug[r][c2] -= fac * prow;
        __syncthreads();
    }
    if (c2 >= 8) Qi[r * 8 + (c2 - 8)] = aug[r][c2];
}

// ---------------------------------------------------------------------------
// Prep 2: fp32 weights -> padded fp16 copies + padded fp32 biases in ws.
// ---------------------------------------------------------------------------
__global__ void prep_kernel(const float* __restrict__ W1, const float* __restrict__ b1,
                            const float* __restrict__ W2, const float* __restrict__ b2,
                            const float* __restrict__ W3, const float* __restrict__ b3,
                            const float* __restrict__ W4, const float* __restrict__ b4,
                            char* __restrict__ ws)
{
    const int idx = blockIdx.x * 256 + threadIdx.x;
    f16* W1h = (f16*)(ws + WS_W1H);
    f16* W2h = (f16*)(ws + WS_W2H);
    f16* W3h = (f16*)(ws + WS_W3H);
    f16* W4h = (f16*)(ws + WS_W4H);
    float* b1p = (float*)(ws + WS_B1P);
    float* b2p = (float*)(ws + WS_B2P);
    float* b3p = (float*)(ws + WS_B3P);
    float* b4p = (float*)(ws + WS_B4P);

    if (idx < 256 * 224) {
        const int n = idx / 224, k = idx - n * 224;
        const bool ok = (n < NH) && (k < NH);
        W2h[idx] = ok ? (f16)W2[n * NH + k] : (f16)0.0f;
        W3h[idx] = ok ? (f16)W3[n * NH + k] : (f16)0.0f;
    }
    if (idx < 256 * 32) {
        const int n = idx >> 5, k = idx & 31;
        W1h[idx] = ((n < NH) && (k < NF)) ? (f16)W1[n * NF + k] : (f16)0.0f;
    }
    if (idx < 16 * 224) {
        const int n = idx / 224, k = idx - n * 224;
        W4h[idx] = ((n < NC) && (k < NH)) ? (f16)W4[n * NH + k] : (f16)0.0f;
    }
    if (idx < 256) {
        b1p[idx] = (idx < NH) ? b1[idx] : 0.0f;
        b2p[idx] = (idx < NH) ? b2[idx] : 0.0f;
        b3p[idx] = (idx < NH) ? b3[idx] : 0.0f;
    }
    if (idx < 16) b4p[idx] = (idx < NC) ? b4[idx] : 0.0f;
}

// ---------------------------------------------------------------------------
// global -> LDS stage of one 256x32-half weight k-tile (16KB), 2 instrs/wave.
// LDS dest is linear (global_load_lds requirement); the 16B-block XOR swizzle
// is pre-applied to the SOURCE address (m173 pattern). swz(n) = (n>>1)&3.
// ---------------------------------------------------------------------------
__device__ __forceinline__ void stage2(const f16* __restrict__ src, int strideH, int ks,
                                       f16* dst, int wid, int lane)
{
#pragma unroll
    for (int i = 0; i < 2; ++i) {
        const int n  = wid * 32 + i * 16 + (lane >> 2);
        const int qs = (lane & 3) ^ ((n >> 1) & 3);
        const f16* s = src + (size_t)n * strideH + ks * 32 + qs * 8;
        f16* d = dst + wid * 1024 + i * 512;
        __builtin_amdgcn_global_load_lds(
            (const __attribute__((address_space(1))) void*)s,
            (__attribute__((address_space(3))) void*)d, 16, 0, 0);
    }
}

// ---------------------------------------------------------------------------
// One MFMA layer: act (hi/lo fp16 in LDS) x fp16 W -> relu -> split -> act.
// Wave tile 64x64 (MT=NT=4). nks ksteps of K=32. Stages next tiles (dbuf).
// ---------------------------------------------------------------------------
__device__ __forceinline__ void mfma_layer(f16* actH, f16* actL,
                                           f16 (*wtile)[NPAD * 32], int& cur,
                                           int nks,
                                           const f16* Wstage_cur, const f16* Wstage_next,
                                           const float* __restrict__ biasP,
                                           int mrow0, int n0, int lane, int wid,
                                           int col16, int kb)
{
    floatx4 acc[4][4];
#pragma unroll
    for (int nt = 0; nt < 4; ++nt) {
        const float b = biasP[n0 + nt * 16 + col16];
#pragma unroll
        for (int mt = 0; mt < 4; ++mt) {
            floatx4 v; v[0] = b; v[1] = b; v[2] = b; v[3] = b;
            acc[mt][nt] = v;
        }
    }
    int aoff[4];
#pragma unroll
    for (int mt = 0; mt < 4; ++mt)
        aoff[mt] = (mrow0 + mt * 16 + col16) * ACT_W + kb * 8;
    int boff[4];
#pragma unroll
    for (int nt = 0; nt < 4; ++nt) {
        const int n = n0 + nt * 16 + col16;
        boff[nt] = n * 32 + ((kb ^ ((n >> 1) & 3)) * 8);
    }

#pragma unroll 1
    for (int ks = 0; ks < nks; ++ks) {
        f16* wt = wtile[cur];
        if (ks + 1 < nks)          stage2(Wstage_cur, KPAD, ks + 1, wtile[cur ^ 1], wid, lane);
        else if (Wstage_next)      stage2(Wstage_next, KPAD, 0,     wtile[cur ^ 1], wid, lane);

        half8 bf[4];
#pragma unroll
        for (int nt = 0; nt < 4; ++nt) bf[nt] = *(const half8*)&wt[boff[nt]];
        half8 ah[4], al[4];
#pragma unroll
        for (int mt = 0; mt < 4; ++mt) {
            ah[mt] = *(const half8*)&actH[aoff[mt] + ks * 32];
            al[mt] = *(const half8*)&actL[aoff[mt] + ks * 32];
        }
#pragma unroll
        for (int mt = 0; mt < 4; ++mt)
#pragma unroll
            for (int nt = 0; nt < 4; ++nt) {
                acc[mt][nt] = __builtin_amdgcn_mfma_f32_16x16x32_f16(ah[mt], bf[nt], acc[mt][nt], 0, 0, 0);
                acc[mt][nt] = __builtin_amdgcn_mfma_f32_16x16x32_f16(al[mt], bf[nt], acc[mt][nt], 0, 0, 0);
            }
        __syncthreads();           // stage complete (vmcnt drain) + all reads done
        cur ^= 1;
    }

    // epilogue: relu, fp16 hi/lo split, in-place act write (own rows/cols only)
#pragma unroll
    for (int nt = 0; nt < 4; ++nt) {
        const int colbase = n0 + nt * 16;
        if (colbase < KPAD) {                     // wave-uniform
            const int col = colbase + col16;
#pragma unroll
            for (int mt = 0; mt < 4; ++mt) {
#pragma unroll
                for (int r = 0; r < 4; ++r) {
                    const int row = mrow0 + mt * 16 + kb * 4 + r;
                    const float v = fmaxf(acc[mt][nt][r], 0.0f);
                    const f16 hi = (f16)v;
                    const f16 lo = (f16)(v - (float)hi);
                    actH[row * ACT_W + col] = hi;
                    actL[row * ACT_W + col] = lo;
                }
            }
        }
    }
    __syncthreads();
}

// ---------------------------------------------------------------------------
// Fused MFMA MLP: head (fc0 + reduced-KKT QP, fp32) -> L1 -> L2 -> L3 -> L4.
// ---------------------------------------------------------------------------
__global__ __launch_bounds__(512, 2)
void mlp_mfma(const float* __restrict__ x,
              const float* __restrict__ W0, const float* __restrict__ b0,
              const char* __restrict__ ws,
              float* __restrict__ out, int B)
{
    __shared__ f16 actH[M_BLK * ACT_W];       // 59392 B
    __shared__ f16 actL[M_BLK * ACT_W];       // 59392 B
    __shared__ f16 wtile[2][NPAD * 32];       // 2 x 16384 B   -> total 151552 B

    const int tid   = threadIdx.x;
    const int lane  = tid & 63;
    const int wid   = __builtin_amdgcn_readfirstlane(tid >> 6);
    const int col16 = lane & 15;
    const int kb    = lane >> 4;
    const int mg    = wid >> 2;               // m-group 0..1
    const int ng    = wid & 3;                // n-group 0..3
    const int mrow0 = mg * 64;
    const int n0    = ng * 64;

    const float* Qi  = (const float*)(ws + WS_QI);
    const float* b1p = (const float*)(ws + WS_B1P);
    const float* b2p = (const float*)(ws + WS_B2P);
    const float* b3p = (const float*)(ws + WS_B3P);
    const float* b4p = (const float*)(ws + WS_B4P);
    const f16*  W1h  = (const f16*)(ws + WS_W1H);
    const f16*  W2h  = (const f16*)(ws + WS_W2H);
    const f16*  W3h  = (const f16*)(ws + WS_W3H);
    const f16*  W4h  = (const f16*)(ws + WS_W4H);

    // prestage W1 tile -> wtile[0], W2 ks0 -> wtile[1] (flies over the head)
    stage2(W1h, 32,   0, &wtile[0][0], wid, lane);
    stage2(W2h, KPAD, 0, &wtile[1][0], wid, lane);

    // ---- head: fc0 + QP (fp32), rows handled by threads 0..127 ----
    if (tid < M_BLK) {
        const long g = (long)blockIdx.x * M_BLK + tid;
        float xr[NF];
        if (g < B) {
            const float4* xp = (const float4*)(x + g * NF);
            const float4 a = xp[0], b = xp[1];
            xr[0] = a.x; xr[1] = a.y; xr[2] = a.z; xr[3] = a.w;
            xr[4] = b.x; xr[5] = b.y; xr[6] = b.z; xr[7] = b.w;
        } else {
#pragma unroll
            for (int i = 0; i < NF; ++i) xr[i] = 0.0f;
        }
        float h[NF];
#pragma unroll
        for (int j = 0; j < NF; ++j) {
            float acc = b0[j];
#pragma unroll
            for (int k = 0; k < NF; ++k) acc = fmaf(W0[j * NF + k], xr[k], acc);
            h[j] = acc;
        }
        // reduced KKT: z = Qi h - Qi A' nu, nu = (A Qi A')^-1 (A Qi h - A h)
        float tq[NF], u0[NF], u1[NF];
        const float h3 = h[3];
#pragma unroll
        for (int i = 0; i < NF; ++i) {
            float s = 0.0f;
#pragma unroll
            for (int k = 0; k < NF; ++k) s = fmaf(Qi[i * NF + k], h[k], s);
            tq[i] = s;
            u0[i] = fmaf(Qi[i * NF + 4], h3, Qi[i * NF + 5]);
            u1[i] = fmaf(Qi[i * NF + 6], h3, Qi[i * NF + 7]);
        }
        const float m00 = fmaf(h3, u0[4], u0[5]);
        const float m01 = fmaf(h3, u1[4], u1[5]);
        const float m10 = fmaf(h3, u0[6], u0[7]);
        const float m11 = fmaf(h3, u1[6], u1[7]);
        const float r0  = fmaf(h3, tq[4], tq[5]) - fmaf(h3, h[4], h[5]);
        const float r1  = fmaf(h3, tq[6], tq[7]) - fmaf(h3, h[6], h[7]);
        const float idet = 1.0f / (m00 * m11 - m01 * m10);
        const float nu0 = (m11 * r0 - m01 * r1) * idet;
        const float nu1 = (m00 * r1 - m10 * r0) * idet;
        float z[NF];
#pragma unroll
        for (int i = 0; i < NF; ++i) z[i] = tq[i] - u0[i] * nu0 - u1[i] * nu1;

        half8 zh, zl, zz;
#pragma unroll
        for (int k = 0; k < 8; ++k) {
            const f16 hi = (f16)z[k];
            zh[k] = hi;
            zl[k] = (f16)(z[k] - (float)hi);
            zz[k] = (f16)0.0f;
        }
        const int base = tid * ACT_W;
        *(half8*)&actH[base + 0]  = zh;
        *(half8*)&actH[base + 8]  = zz;
        *(half8*)&actH[base + 16] = zz;
        *(half8*)&actH[base + 24] = zz;
        *(half8*)&actL[base + 0]  = zl;
        *(half8*)&actL[base + 8]  = zz;
        *(half8*)&actL[base + 16] = zz;
        *(half8*)&actL[base + 24] = zz;
    }
    __syncthreads();   // head acts + prestaged W1/W2ks0 all visible

    int cur = 0;
    // L1: 8->200 (K padded to 32, 1 kstep). W2 ks1 gets staged by L2's first iter.
    mfma_layer(actH, actL, wtile, cur, 1, (const f16*)0, (const f16*)0,
               b1p, mrow0, n0, lane, wid, col16, kb);
    // L2: 200->200, stages W2 ks1..6 then W3 ks0
    mfma_layer(actH, actL, wtile, cur, 7, W2h, W3h,
               b2p, mrow0, n0, lane, wid, col16, kb);
    // L3: 200->200, stages W3 ks1..6
    mfma_layer(actH, actL, wtile, cur, 7, W3h, (const f16*)0,
               b3p, mrow0, n0, lane, wid, col16, kb);

    // ---- L4: 200->8 ; wave = m-tile wid, B-frags direct from global (L2-hot) ----
    {
        const int aoffm = (wid * 16 + col16) * ACT_W + kb * 8;
        const float bb = b4p[col16];
        floatx4 acc; acc[0] = bb; acc[1] = bb; acc[2] = bb; acc[3] = bb;
        const f16* w4 = W4h + col16 * KPAD + kb * 8;
#pragma unroll 1
        for (int ks = 0; ks < 7; ++ks) {
            const half8 bf = *(const half8*)(w4 + ks * 32);
            const half8 ah = *(const half8*)&actH[aoffm + ks * 32];
            const half8 al = *(const half8*)&actL[aoffm + ks * 32];
            acc = __builtin_amdgcn_mfma_f32_16x16x32_f16(ah, bf, acc, 0, 0, 0);
            acc = __builtin_amdgcn_mfma_f32_16x16x32_f16(al, bf, acc, 0, 0, 0);
        }
        if (col16 < NC) {
            const long grow = (long)blockIdx.x * M_BLK + wid * 16 + kb * 4;
#pragma unroll
            for (int r = 0; r < 4; ++r) {
                const long g = grow + r;
                if (g < B) out[g * NC + col16] = acc[r];
            }
        }
    }
}

// ===========================================================================
// Fallback fp32 path (round-0 kernel) if ws_size is too small for prep data.
// ===========================================================================
#define BT 64
#define NWAVE 8
#define JB 25
#define CH 8

__device__ __forceinline__ void layer200(const float* __restrict__ in_,
                                         float* __restrict__ out_,
                                         const float* __restrict__ W,
                                         const float* __restrict__ bias,
                                         int j0, int lane)
{
    float acc[JB];
#pragma unroll
    for (int jj = 0; jj < JB; ++jj) acc[jj] = bias[j0 + jj];
#pragma unroll 1
    for (int k0 = 0; k0 < NH; k0 += CH) {
        float a[CH];
#pragma unroll
        for (int u = 0; u < CH; ++u) a[u] = in_[(k0 + u) * BT + lane];
#pragma unroll
        for (int jj = 0; jj < JB; ++jj) {
            const float* wr = W + (j0 + jj) * NH + k0;
#pragma unroll
            for (int u = 0; u < CH; ++u) acc[jj] = fmaf(wr[u], a[u], acc[jj]);
        }
    }
#pragma unroll
    for (int jj = 0; jj < JB; ++jj)
        out_[(j0 + jj) * BT + lane] = fmaxf(acc[jj], 0.0f);
}

__global__ __launch_bounds__(BT * NWAVE, 2)
void mlp_fused(const float* __restrict__ x, const float* __restrict__ Qi,
               const float* __restrict__ W0, const float* __restrict__ b0,
               const float* __restrict__ W1, const float* __restrict__ b1,
               const float* __restrict__ W2, const float* __restrict__ b2,
               const float* __restrict__ W3, const float* __restrict__ b3,
               const float* __restrict__ W4, const float* __restrict__ b4,
               float* __restrict__ out, int B)
{
    __shared__ float actA[NH * BT];
    __shared__ float actB[NH * BT];
    __shared__ float outP[NWAVE * NC * BT];

    const int lane = threadIdx.x & 63;
    const int wid  = __builtin_amdgcn_readfirstlane((int)(threadIdx.x >> 6));
    const int g    = blockIdx.x * BT + lane;
    const int j0   = wid * JB;

    float xr[NF];
    if (g < B) {
        const float4* xp = reinterpret_cast<const float4*>(x + (size_t)g * NF);
        float4 x0 = xp[0], x1 = xp[1];
        xr[0] = x0.x; xr[1] = x0.y; xr[2] = x0.z; xr[3] = x0.w;
        xr[4] = x1.x; xr[5] = x1.y; xr[6] = x1.z; xr[7] = x1.w;
    } else {
#pragma unroll
        for (int i = 0; i < NF; ++i) xr[i] = 0.0f;
    }
    float h[NF];
#pragma unroll
    for (int j = 0; j < NF; ++j) {
        float acc = b0[j];
#pragma unroll
        for (int k = 0; k < NF; ++k) acc = fmaf(W0[j * NF + k], xr[k], acc);
        h[j] = acc;
    }
    float tq[NF], u0[NF], u1[NF];
    const float h3 = h[3];
#pragma unroll
    for (int i = 0; i < NF; ++i) {
        float s = 0.0f;
#pragma unroll
        for (int k = 0; k < NF; ++k) s = fmaf(Qi[i * NF + k], h[k], s);
        tq[i] = s;
        u0[i] = fmaf(Qi[i * NF + 4], h3, Qi[i * NF + 5]);
        u1[i] = fmaf(Qi[i * NF + 6], h3, Qi[i * NF + 7]);
    }
    const float m00 = fmaf(h3, u0[4], u0[5]);
    const float m01 = fmaf(h3, u1[4], u1[5]);
    const float m10 = fmaf(h3, u0[6], u0[7]);
    const float m11 = fmaf(h3, u1[6], u1[7]);
    const float r0  = fmaf(h3, tq[4], tq[5]) - fmaf(h3, h[4], h[5]);
    const float r1  = fmaf(h3, tq[6], tq[7]) - fmaf(h3, h[6], h[7]);
    const float idet = 1.0f / (m00 * m11 - m01 * m10);
    const float nu0 = (m11 * r0 - m01 * r1) * idet;
    const float nu1 = (m00 * r1 - m10 * r0) * idet;
    float z[NF];
#pragma unroll
    for (int i = 0; i < NF; ++i) z[i] = tq[i] - u0[i] * nu0 - u1[i] * nu1;

#pragma unroll
    for (int jj = 0; jj < JB; ++jj) {
        const int j = j0 + jj;
        float acc = b1[j];
#pragma unroll
        for (int k = 0; k < NF; ++k) acc = fmaf(W1[j * NF + k], z[k], acc);
        actA[j * BT + lane] = fmaxf(acc, 0.0f);
    }
    __syncthreads();
    layer200(actA, actB, W2, b2, j0, lane);
    __syncthreads();
    layer200(actB, actA, W3, b3, j0, lane);
    __syncthreads();
    {
        float a[JB];
#pragma unroll
        for (int kk = 0; kk < JB; ++kk) a[kk] = actA[(j0 + kk) * BT + lane];
        float acc[NC];
#pragma unroll
        for (int o = 0; o < NC; ++o) acc[o] = 0.0f;
#pragma unroll
        for (int o = 0; o < NC; ++o) {
            const float* wr = W4 + o * NH + j0;
#pragma unroll
            for (int kk = 0; kk < JB; ++kk) acc[o] = fmaf(wr[kk], a[kk], acc[o]);
        }
#pragma unroll
        for (int o = 0; o < NC; ++o) outP[(wid * NC + o) * BT + lane] = acc[o];
    }
    __syncthreads();
    {
        float s = b4[wid];
#pragma unroll
        for (int w = 0; w < NWAVE; ++w) s += outP[(w * NC + wid) * BT + lane];
        if (g < B) out[(size_t)g * NC + wid] = s;
    }
}

// ===========================================================================
extern "C" void kernel_launch(void* const* d_in, const int* in_sizes, int n_in,
                              void* d_out, int out_size, void* d_ws, size_t ws_size,
                              hipStream_t stream)
{
    const float* x  = (const float*)d_in[0];
    const float* Q  = (const float*)d_in[1];
    const float* W0 = (const float*)d_in[2];
    const float* b0 = (const float*)d_in[3];
    const float* W1 = (const float*)d_in[4];
    const float* b1 = (const float*)d_in[5];
    const float* W2 = (const float*)d_in[6];
    const float* b2 = (const float*)d_in[7];
    const float* W3 = (const float*)d_in[8];
    const float* b3 = (const float*)d_in[9];
    const float* W4 = (const float*)d_in[10];
    const float* b4 = (const float*)d_in[11];
    float* out = (float*)d_out;
    float* Qi  = (float*)d_ws;

    const int B = in_sizes[0] / NF;

    hipLaunchKernelGGL(qinv_kernel, dim3(1), dim3(128), 0, stream, Q, Qi);

    if (ws_size >= WS_NEED) {
        hipLaunchKernelGGL(prep_kernel, dim3(224), dim3(256), 0, stream,
                           W1, b1, W2, b2, W3, b3, W4, b4, (char*)d_ws);
        hipLaunchKernelGGL(mlp_mfma, dim3((B + M_BLK - 1) / M_BLK), dim3(512), 0, stream,
                           x, W0, b0, (const char*)d_ws, out, B);
    } else {
        hipLaunchKernelGGL(mlp_fused, dim3((B + BT - 1) / BT), dim3(BT * NWAVE), 0, stream,
                           x, Qi, W0, b0, W1, b1, W2, b2, W3, b3, W4, b4, out, B);
    }
}

// Round 3
// 61.122 us; speedup vs baseline: 11.3252x; 1.5461x over previous
//
#include <hip/hip_runtime.h>
#include <math.h>

typedef _Float16 f16;
typedef f16 half8 __attribute__((ext_vector_type(8)));
typedef float floatx4 __attribute__((ext_vector_type(4)));

#define NF 8
#define NH 200
#define NC 8
#define M_BLK 64
#define ACT_W 232          // 224 data + 8 pad halfs; 464B row stride (29x16B == 5 mod 8 -> ~conflict-free b128)
#define NKT 13             // n-tiles covering 208 cols (200 valid)

// ---- d_ws byte layout ----
#define WS_QI   0          // 64 f32
#define WS_B1P  256        // 224 f32
#define WS_B2P  1152       // 224 f32
#define WS_B3P  2048       // 224 f32
#define WS_WP1  3008       // f16 frag-packed [1ks][13nt][64][8]  = 13312 B
#define WS_WP2  16320      // f16 [7][13][64][8] = 93184 B
#define WS_WP3  109504     // f16 [7][13][64][8] = 93184 B
#define WS_WP4  202688     // f16 [7][1][64][8]  = 7168 B
#define WS_NEED 209856

// ---------------------------------------------------------------------------
// Prep 1: invert Q (8x8) Gauss-Jordan w/ pivoting. Exact identity for Q=I.
// ---------------------------------------------------------------------------
__global__ void qinv_kernel(const float* __restrict__ Q, float* __restrict__ Qi)
{
    __shared__ float aug[8][16];
    __shared__ int piv;
    const int t  = threadIdx.x;
    const int r  = t >> 4;
    const int c2 = t & 15;
    aug[r][c2] = (c2 < 8) ? Q[r * 8 + c2] : ((c2 - 8 == r) ? 1.0f : 0.0f);
    __syncthreads();
    for (int c = 0; c < 8; ++c) {
        if (t == 0) {
            int p = c; float best = fabsf(aug[c][c]);
            for (int rr = c + 1; rr < 8; ++rr) {
                float v = fabsf(aug[rr][c]);
                if (v > best) { best = v; p = rr; }
            }
            piv = p;
        }
        __syncthreads();
        const int p = piv;
        float myv = aug[r][c2];
        __syncthreads();
        if (r == c)      aug[p][c2] = myv;
        else if (r == p) aug[c][c2] = myv;
        __syncthreads();
        const float pv = aug[c][c];
        __syncthreads();
        if (r == c) aug[r][c2] = aug[r][c2] / pv;
        __syncthreads();
        const float fac  = (r == c) ? 0.0f : aug[r][c];
        const float prow = aug[c][c2];
        __syncthreads();
        aug[r][c2] -= fac * prow;
        __syncthreads();
    }
    if (c2 >= 8) Qi[r * 8 + (c2 - 8)] = aug[r][c2];
}

// ---------------------------------------------------------------------------
// Prep 2: pack fp32 weights into B-fragment order:
//   dst[((ks*nkt + nt)*64 + lane)*8 + j] = W[nt*16 + (lane&15)][ks*32 + (lane>>4)*8 + j]
// so a wave's B-frag load for (ks,nt) is one coalesced 1KB global_load_dwordx4.
// ---------------------------------------------------------------------------
__device__ __forceinline__ void pack_frag(const float* __restrict__ W, int Nv, int Kv,
                                          int nkt, int nks, f16* __restrict__ dst, int gid)
{
    if (gid < nks * nkt * 64) {
        const int ks    = gid / (nkt * 64);
        const int rem   = gid - ks * nkt * 64;
        const int nt    = rem >> 6;
        const int lane  = rem & 63;
        const int n     = nt * 16 + (lane & 15);
        const int kbase = ks * 32 + ((lane >> 4) * 8);
        f16 tmp[8];
#pragma unroll
        for (int j = 0; j < 8; ++j) {
            const int k = kbase + j;
            tmp[j] = (n < Nv && k < Kv) ? (f16)W[n * Kv + k] : (f16)0.0f;
        }
        *(half8*)&dst[(size_t)gid * 8] = *(const half8*)tmp;
    }
}

__global__ void prep_kernel(const float* __restrict__ W1, const float* __restrict__ b1,
                            const float* __restrict__ W2, const float* __restrict__ b2,
                            const float* __restrict__ W3, const float* __restrict__ b3,
                            const float* __restrict__ W4,
                            char* __restrict__ ws)
{
    const int gid = blockIdx.x * 256 + threadIdx.x;   // up to 5888
    pack_frag(W1, NH, NF, NKT, 1, (f16*)(ws + WS_WP1), gid);
    pack_frag(W2, NH, NH, NKT, 7, (f16*)(ws + WS_WP2), gid);
    pack_frag(W3, NH, NH, NKT, 7, (f16*)(ws + WS_WP3), gid);
    pack_frag(W4, NC, NH, 1,   7, (f16*)(ws + WS_WP4), gid);
    if (gid < 224) {
        ((float*)(ws + WS_B1P))[gid] = (gid < NH) ? b1[gid] : 0.0f;
        ((float*)(ws + WS_B2P))[gid] = (gid < NH) ? b2[gid] : 0.0f;
        ((float*)(ws + WS_B3P))[gid] = (gid < NH) ? b3[gid] : 0.0f;
    }
}

// ---------------------------------------------------------------------------
// One layer: act(LDS,f16) x Wp(global,frag-packed f16) -> relu -> act out.
// Wave (mg,ng): rows [mg*32, mg*32+32), n-tiles {ng, ng+4, ng+8, ng+12}<13.
// No barriers inside; B-frags prefetched one kstep ahead.
// ---------------------------------------------------------------------------
__device__ __forceinline__ void layerN(const f16* __restrict__ actIn, f16* __restrict__ actOut,
                                       const f16* __restrict__ Wp, const float* __restrict__ biasP,
                                       const int nks, const int mg, const int ng, const int lane)
{
    const int col16 = lane & 15;
    const int kb8   = (lane >> 4) * 8;

    floatx4 acc[2][4];
#pragma unroll
    for (int i = 0; i < 4; ++i) {
        const int nt = ng + 4 * i;
        if (nt < NKT) {
            const float b = biasP[nt * 16 + col16];
            floatx4 v; v[0] = b; v[1] = b; v[2] = b; v[3] = b;
            acc[0][i] = v; acc[1][i] = v;
        }
    }
    const int aoff = (mg * 32 + col16) * ACT_W + kb8;

    half8 bf[4];
#pragma unroll
    for (int i = 0; i < 4; ++i) {
        const int nt = ng + 4 * i;
        if (nt < NKT) bf[i] = *(const half8*)&Wp[((size_t)nt * 64 + lane) * 8];
    }

#pragma unroll 1
    for (int ks = 0; ks < nks; ++ks) {
        const half8 a0 = *(const half8*)&actIn[aoff + ks * 32];
        const half8 a1 = *(const half8*)&actIn[aoff + 16 * ACT_W + ks * 32];
        half8 cur[4];
#pragma unroll
        for (int i = 0; i < 4; ++i) cur[i] = bf[i];
        if (ks + 1 < nks) {
#pragma unroll
            for (int i = 0; i < 4; ++i) {
                const int nt = ng + 4 * i;
                if (nt < NKT)
                    bf[i] = *(const half8*)&Wp[((size_t)((ks + 1) * NKT + nt) * 64 + lane) * 8];
            }
        }
#pragma unroll
        for (int i = 0; i < 4; ++i) {
            const int nt = ng + 4 * i;
            if (nt < NKT) {
                acc[0][i] = __builtin_amdgcn_mfma_f32_16x16x32_f16(a0, cur[i], acc[0][i], 0, 0, 0);
                acc[1][i] = __builtin_amdgcn_mfma_f32_16x16x32_f16(a1, cur[i], acc[1][i], 0, 0, 0);
            }
        }
    }

    // epilogue: relu + single-f16 store (C layout: col=lane&15, row=(lane>>4)*4+r)
#pragma unroll
    for (int i = 0; i < 4; ++i) {
        const int nt = ng + 4 * i;
        if (nt < NKT) {
            const int col = nt * 16 + col16;
#pragma unroll
            for (int mt = 0; mt < 2; ++mt) {
#pragma unroll
                for (int r = 0; r < 4; ++r) {
                    const int row = mg * 32 + mt * 16 + (lane >> 4) * 4 + r;
                    actOut[row * ACT_W + col] = (f16)fmaxf(acc[mt][i][r], 0.0f);
                }
            }
        }
    }
}

// ---------------------------------------------------------------------------
// Fused MLP: head (fc0 + reduced-KKT QP, fp32) -> L1 -> L2 -> L3 -> L4.
// 64 rows/block, 8 waves, act ping-pong in LDS, 5 barriers total.
// ---------------------------------------------------------------------------
__global__ __launch_bounds__(512, 2)
void mlp_mfma(const float* __restrict__ x,
              const float* __restrict__ W0, const float* __restrict__ b0,
              const float* __restrict__ b4,
              const char* __restrict__ ws,
              float* __restrict__ out, int B)
{
    __shared__ __align__(16) char smem[2 * M_BLK * ACT_W * 2];   // 59392 B
    f16* actA = (f16*)smem;
    f16* actB = (f16*)(smem + M_BLK * ACT_W * 2);
    float* outP = (float*)smem;   // overlay on actA, used after L3 (7*64*16 f32 = 28672 B)

    const int tid   = threadIdx.x;
    const int lane  = tid & 63;
    const int wid   = __builtin_amdgcn_readfirstlane(tid >> 6);
    const int col16 = lane & 15;
    const int kb    = lane >> 4;
    const int mg    = wid >> 2;
    const int ng    = wid & 3;

    const float* Qi  = (const float*)(ws + WS_QI);
    const float* b1p = (const float*)(ws + WS_B1P);
    const float* b2p = (const float*)(ws + WS_B2P);
    const float* b3p = (const float*)(ws + WS_B3P);
    const f16*  Wp1  = (const f16*)(ws + WS_WP1);
    const f16*  Wp2  = (const f16*)(ws + WS_WP2);
    const f16*  Wp3  = (const f16*)(ws + WS_WP3);
    const f16*  Wp4  = (const f16*)(ws + WS_WP4);

    // zero cols [208,232) of both act buffers (stay zero for the whole kernel)
    if (tid < 384) {
        const int b = tid / 192;
        const int r = (tid % 192) / 3;
        const int c = tid % 3;
        f16* dst = (b ? actB : actA) + r * ACT_W + 208 + c * 8;
        half8 z = {};
        *(half8*)dst = z;
    }

    // ---- head: fc0 + QP (fp32), one row per thread 0..63 ----
    if (tid < M_BLK) {
        const long g = (long)blockIdx.x * M_BLK + tid;
        float xr[NF];
        if (g < B) {
            const float4* xp = (const float4*)(x + g * NF);
            const float4 a = xp[0], b = xp[1];
            xr[0] = a.x; xr[1] = a.y; xr[2] = a.z; xr[3] = a.w;
            xr[4] = b.x; xr[5] = b.y; xr[6] = b.z; xr[7] = b.w;
        } else {
#pragma unroll
            for (int i = 0; i < NF; ++i) xr[i] = 0.0f;
        }
        float h[NF];
#pragma unroll
        for (int j = 0; j < NF; ++j) {
            float acc = b0[j];
#pragma unroll
            for (int k = 0; k < NF; ++k) acc = fmaf(W0[j * NF + k], xr[k], acc);
            h[j] = acc;
        }
        // reduced KKT: z = Qi h - Qi A' nu, nu = (A Qi A')^-1 (A Qi h - A h); Q=I => z=h
        float tq[NF], u0[NF], u1[NF];
        const float h3 = h[3];
#pragma unroll
        for (int i = 0; i < NF; ++i) {
            float s = 0.0f;
#pragma unroll
            for (int k = 0; k < NF; ++k) s = fmaf(Qi[i * NF + k], h[k], s);
            tq[i] = s;
            u0[i] = fmaf(Qi[i * NF + 4], h3, Qi[i * NF + 5]);
            u1[i] = fmaf(Qi[i * NF + 6], h3, Qi[i * NF + 7]);
        }
        const float m00 = fmaf(h3, u0[4], u0[5]);
        const float m01 = fmaf(h3, u1[4], u1[5]);
        const float m10 = fmaf(h3, u0[6], u0[7]);
        const float m11 = fmaf(h3, u1[6], u1[7]);
        const float r0  = fmaf(h3, tq[4], tq[5]) - fmaf(h3, h[4], h[5]);
        const float r1  = fmaf(h3, tq[6], tq[7]) - fmaf(h3, h[6], h[7]);
        const float idet = 1.0f / (m00 * m11 - m01 * m10);
        const float nu0 = (m11 * r0 - m01 * r1) * idet;
        const float nu1 = (m00 * r1 - m10 * r0) * idet;

        half8 zh, zz;
#pragma unroll
        for (int k = 0; k < 8; ++k) {
            zh[k] = (f16)(tq[k] - u0[k] * nu0 - u1[k] * nu1);
            zz[k] = (f16)0.0f;
        }
        const int base = tid * ACT_W;
        *(half8*)&actA[base + 0]  = zh;
        *(half8*)&actA[base + 8]  = zz;
        *(half8*)&actA[base + 16] = zz;
        *(half8*)&actA[base + 24] = zz;
    }
    __syncthreads();                                   // B1

    layerN(actA, actB, Wp1, b1p, 1, mg, ng, lane);     // L1: 8(32)->208
    __syncthreads();                                   // B2
    layerN(actB, actA, Wp2, b2p, 7, mg, ng, lane);     // L2: 224->208
    __syncthreads();                                   // B3
    layerN(actA, actB, Wp3, b3p, 7, mg, ng, lane);     // L3: 224->208
    __syncthreads();                                   // B4

    // ---- L4: 200->8 ; wave w handles kstep w (w<7), partials into outP ----
    if (wid < 7) {
        const int ks = wid;
        const half8 bf4 = *(const half8*)&Wp4[((size_t)ks * 64 + lane) * 8];
#pragma unroll
        for (int mt = 0; mt < 4; ++mt) {
            const half8 am = *(const half8*)&actB[(mt * 16 + col16) * ACT_W + kb * 8 + ks * 32];
            floatx4 acc = {};
            acc = __builtin_amdgcn_mfma_f32_16x16x32_f16(am, bf4, acc, 0, 0, 0);
#pragma unroll
            for (int r = 0; r < 4; ++r)
                outP[(ks * 64 + mt * 16 + kb * 4 + r) * 16 + col16] = acc[r];
        }
    }
    __syncthreads();                                   // B5

    // ---- reduce 7 partials + bias, store ----
    {
        const int row = tid >> 3;
        const int col = tid & 7;
        float s = b4[col];
#pragma unroll
        for (int w = 0; w < 7; ++w) s += outP[(w * 64 + row) * 16 + col];
        const long g = (long)blockIdx.x * M_BLK + row;
        if (g < B) out[g * NC + col] = s;
    }
}

// ===========================================================================
// Fallback fp32 path (round-0 kernel) if ws_size is too small for prep data.
// ===========================================================================
#define BT 64
#define NWAVE 8
#define JB 25
#define CH 8

__device__ __forceinline__ void layer200(const float* __restrict__ in_,
                                         float* __restrict__ out_,
                                         const float* __restrict__ W,
                                         const float* __restrict__ bias,
                                         int j0, int lane)
{
    float acc[JB];
#pragma unroll
    for (int jj = 0; jj < JB; ++jj) acc[jj] = bias[j0 + jj];
#pragma unroll 1
    for (int k0 = 0; k0 < NH; k0 += CH) {
        float a[CH];
#pragma unroll
        for (int u = 0; u < CH; ++u) a[u] = in_[(k0 + u) * BT + lane];
#pragma unroll
        for (int jj = 0; jj < JB; ++jj) {
            const float* wr = W + (j0 + jj) * NH + k0;
#pragma unroll
            for (int u = 0; u < CH; ++u) acc[jj] = fmaf(wr[u], a[u], acc[jj]);
        }
    }
#pragma unroll
    for (int jj = 0; jj < JB; ++jj)
        out_[(j0 + jj) * BT + lane] = fmaxf(acc[jj], 0.0f);
}

__global__ __launch_bounds__(BT * NWAVE, 2)
void mlp_fused(const float* __restrict__ x, const float* __restrict__ Qi,
               const float* __restrict__ W0, const float* __restrict__ b0,
               const float* __restrict__ W1, const float* __restrict__ b1,
               const float* __restrict__ W2, const float* __restrict__ b2,
               const float* __restrict__ W3, const float* __restrict__ b3,
               const float* __restrict__ W4, const float* __restrict__ b4,
               float* __restrict__ out, int B)
{
    __shared__ float actA[NH * BT];
    __shared__ float actB[NH * BT];
    __shared__ float outP[NWAVE * NC * BT];

    const int lane = threadIdx.x & 63;
    const int wid  = __builtin_amdgcn_readfirstlane((int)(threadIdx.x >> 6));
    const int g    = blockIdx.x * BT + lane;
    const int j0   = wid * JB;

    float xr[NF];
    if (g < B) {
        const float4* xp = reinterpret_cast<const float4*>(x + (size_t)g * NF);
        float4 x0 = xp[0], x1 = xp[1];
        xr[0] = x0.x; xr[1] = x0.y; xr[2] = x0.z; xr[3] = x0.w;
        xr[4] = x1.x; xr[5] = x1.y; xr[6] = x1.z; xr[7] = x1.w;
    } else {
#pragma unroll
        for (int i = 0; i < NF; ++i) xr[i] = 0.0f;
    }
    float h[NF];
#pragma unroll
    for (int j = 0; j < NF; ++j) {
        float acc = b0[j];
#pragma unroll
        for (int k = 0; k < NF; ++k) acc = fmaf(W0[j * NF + k], xr[k], acc);
        h[j] = acc;
    }
    float tq[NF], u0[NF], u1[NF];
    const float h3 = h[3];
#pragma unroll
    for (int i = 0; i < NF; ++i) {
        float s = 0.0f;
#pragma unroll
        for (int k = 0; k < NF; ++k) s = fmaf(Qi[i * NF + k], h[k], s);
        tq[i] = s;
        u0[i] = fmaf(Qi[i * NF + 4], h3, Qi[i * NF + 5]);
        u1[i] = fmaf(Qi[i * NF + 6], h3, Qi[i * NF + 7]);
    }
    const float m00 = fmaf(h3, u0[4], u0[5]);
    const float m01 = fmaf(h3, u1[4], u1[5]);
    const float m10 = fmaf(h3, u0[6], u0[7]);
    const float m11 = fmaf(h3, u1[6], u1[7]);
    const float r0  = fmaf(h3, tq[4], tq[5]) - fmaf(h3, h[4], h[5]);
    const float r1  = fmaf(h3, tq[6], tq[7]) - fmaf(h3, h[6], h[7]);
    const float idet = 1.0f / (m00 * m11 - m01 * m10);
    const float nu0 = (m11 * r0 - m01 * r1) * idet;
    const float nu1 = (m00 * r1 - m10 * r0) * idet;
    float z[NF];
#pragma unroll
    for (int i = 0; i < NF; ++i) z[i] = tq[i] - u0[i] * nu0 - u1[i] * nu1;

#pragma unroll
    for (int jj = 0; jj < JB; ++jj) {
        const int j = j0 + jj;
        float acc = b1[j];
#pragma unroll
        for (int k = 0; k < NF; ++k) acc = fmaf(W1[j * NF + k], z[k], acc);
        actA[j * BT + lane] = fmaxf(acc, 0.0f);
    }
    __syncthreads();
    layer200(actA, actB, W2, b2, j0, lane);
    __syncthreads();
    layer200(actB, actA, W3, b3, j0, lane);
    __syncthreads();
    {
        float a[JB];
#pragma unroll
        for (int kk = 0; kk < JB; ++kk) a[kk] = actA[(j0 + kk) * BT + lane];
        float acc[NC];
#pragma unroll
        for (int o = 0; o < NC; ++o) acc[o] = 0.0f;
#pragma unroll
        for (int o = 0; o < NC; ++o) {
            const float* wr = W4 + o * NH + j0;
#pragma unroll
            for (int kk = 0; kk < JB; ++kk) acc[o] = fmaf(wr[kk], a[kk], acc[o]);
        }
#pragma unroll
        for (int o = 0; o < NC; ++o) outP[(wid * NC + o) * BT + lane] = acc[o];
    }
    __syncthreads();
    {
        float s = b4[wid];
#pragma unroll
        for (int w = 0; w < NWAVE; ++w) s += outP[(w * NC + wid) * BT + lane];
        if (g < B) out[(size_t)g * NC + wid] = s;
    }
}

// ===========================================================================
extern "C" void kernel_launch(void* const* d_in, const int* in_sizes, int n_in,
                              void* d_out, int out_size, void* d_ws, size_t ws_size,
                              hipStream_t stream)
{
    const float* x  = (const float*)d_in[0];
    const float* Q  = (const float*)d_in[1];
    const float* W0 = (const float*)d_in[2];
    const float* b0 = (const float*)d_in[3];
    const float* W1 = (const float*)d_in[4];
    const float* b1 = (const float*)d_in[5];
    const float* W2 = (const float*)d_in[6];
    const float* b2 = (const float*)d_in[7];
    const float* W3 = (const float*)d_in[8];
    const float* b3 = (const float*)d_in[9];
    const float* W4 = (const float*)d_in[10];
    const float* b4 = (const float*)d_in[11];
    float* out = (float*)d_out;
    float* Qi  = (float*)d_ws;

    const int B = in_sizes[0] / NF;

    hipLaunchKernelGGL(qinv_kernel, dim3(1), dim3(128), 0, stream, Q, Qi);

    if (ws_size >= WS_NEED) {
        hipLaunchKernelGGL(prep_kernel, dim3(23), dim3(256), 0, stream,
                           W1, b1, W2, b2, W3, b3, W4, (char*)d_ws);
        hipLaunchKernelGGL(mlp_mfma, dim3((B + M_BLK - 1) / M_BLK), dim3(512), 0, stream,
                           x, W0, b0, b4, (const char*)d_ws, out, B);
    } else {
        hipLaunchKernelGGL(mlp_fused, dim3((B + BT - 1) / BT), dim3(BT * NWAVE), 0, stream,
                           x, Qi, W0, b0, W1, b1, W2, b2, W3, b3, W4, b4, out, B);
    }
}

// Round 4
// 52.740 us; speedup vs baseline: 13.1251x; 1.1589x over previous
//
#include <hip/hip_runtime.h>
#include <math.h>

typedef _Float16 f16;
typedef f16 half8 __attribute__((ext_vector_type(8)));
typedef float floatx4 __attribute__((ext_vector_type(4)));

#define NF 8
#define NH 200
#define NC 8
#define M_BLK 256          // rows per block (4 waves x 64 rows)
#define SCR_W 40           // scratch row stride in halfs (80B: 16B-aligned, 20-bank spread)

// ---- d_ws byte layout (same as R3) ----
#define WS_QI   0          // 64 f32
#define WS_B1P  256        // 224 f32 padded bias
#define WS_B2P  1152
#define WS_B3P  2048
#define WS_WP1  3008       // f16 frag-packed [1ks][13nt][64][8]  = 13312 B
#define WS_WP2  16320      // f16 [7][13][64][8] = 93184 B
#define WS_WP3  109504     // f16 [7][13][64][8] = 93184 B
#define WS_WP4  202688     // f16 [7][1][64][8]  = 7168 B
#define WS_NEED 209856

// ---------------------------------------------------------------------------
// Prep (merged): block 0 also inverts Q (Gauss-Jordan w/ pivoting; exact
// identity for Q=I). All blocks pack fp32 weights into B-fragment order:
//   dst[((ks*nkt+nt)*64+lane)*8+j] = W[nt*16+(lane&15)][ks*32+(lane>>4)*8+j]
// so a wave's B-frag load is one coalesced 1KB global_load_dwordx4.
// ---------------------------------------------------------------------------
__device__ __forceinline__ void pack_frag(const float* __restrict__ W, int Nv, int Kv,
                                          int nkt, int nks, f16* __restrict__ dst, int gid)
{
    if (gid < nks * nkt * 64) {
        const int ks    = gid / (nkt * 64);
        const int rem   = gid - ks * nkt * 64;
        const int nt    = rem >> 6;
        const int lane  = rem & 63;
        const int n     = nt * 16 + (lane & 15);
        const int kbase = ks * 32 + ((lane >> 4) * 8);
        f16 tmp[8];
#pragma unroll
        for (int j = 0; j < 8; ++j) {
            const int k = kbase + j;
            tmp[j] = (n < Nv && k < Kv) ? (f16)W[n * Kv + k] : (f16)0.0f;
        }
        *(half8*)&dst[(size_t)gid * 8] = *(const half8*)tmp;
    }
}

__global__ void prep_kernel(const float* __restrict__ Q,
                            const float* __restrict__ W1, const float* __restrict__ b1,
                            const float* __restrict__ W2, const float* __restrict__ b2,
                            const float* __restrict__ W3, const float* __restrict__ b3,
                            const float* __restrict__ W4,
                            char* __restrict__ ws)
{
    const int gid = blockIdx.x * 256 + threadIdx.x;   // up to 5888
    pack_frag(W1, NH, NF, 13, 1, (f16*)(ws + WS_WP1), gid);
    pack_frag(W2, NH, NH, 13, 7, (f16*)(ws + WS_WP2), gid);
    pack_frag(W3, NH, NH, 13, 7, (f16*)(ws + WS_WP3), gid);
    pack_frag(W4, NC, NH, 1,  7, (f16*)(ws + WS_WP4), gid);
    if (gid < 224) {
        ((float*)(ws + WS_B1P))[gid] = (gid < NH) ? b1[gid] : 0.0f;
        ((float*)(ws + WS_B2P))[gid] = (gid < NH) ? b2[gid] : 0.0f;
        ((float*)(ws + WS_B3P))[gid] = (gid < NH) ? b3[gid] : 0.0f;
    }

    if (blockIdx.x == 0) {
        // Q inverse via Gauss-Jordan, threads 0..127 active, all 256 hit barriers
        __shared__ float aug[8][16];
        __shared__ int piv;
        float* Qi = (float*)(ws + WS_QI);
        const int t  = threadIdx.x;
        const bool a = t < 128;
        const int r  = (t >> 4) & 7;
        const int c2 = t & 15;
        if (a) aug[r][c2] = (c2 < 8) ? Q[r * 8 + c2] : ((c2 - 8 == r) ? 1.0f : 0.0f);
        __syncthreads();
        for (int c = 0; c < 8; ++c) {
            if (t == 0) {
                int p = c; float best = fabsf(aug[c][c]);
                for (int rr = c + 1; rr < 8; ++rr) {
                    float v = fabsf(aug[rr][c]);
                    if (v > best) { best = v; p = rr; }
                }
                piv = p;
            }
            __syncthreads();
            const int p = piv;
            float myv = a ? aug[r][c2] : 0.0f;
            __syncthreads();
            if (a) {
                if (r == c)      aug[p][c2] = myv;
                else if (r == p) aug[c][c2] = myv;
            }
            __syncthreads();
            const float pv = aug[c][c];
            __syncthreads();
            if (a && r == c) aug[r][c2] = aug[r][c2] / pv;
            __syncthreads();
            const float fac  = (a && r != c) ? aug[r][c] : 0.0f;
            const float prow = aug[c][c2];
            __syncthreads();
            if (a) aug[r][c2] -= fac * prow;
            __syncthreads();
        }
        if (a && c2 >= 8) Qi[r * 8 + (c2 - 8)] = aug[r][c2];
    }
}

// ---------------------------------------------------------------------------
// One slab layer: aIn (regs, frag-packed) x Wp (global, frag-packed) -> relu
// -> aOut (regs), transposing each 32-col pass through wave-private scratch.
// Fully static-unrolled (rule #20: no runtime indexing of reg arrays).
// ---------------------------------------------------------------------------
template<int NKS>
__device__ __forceinline__ void layer_slab(const f16* __restrict__ Wp,
                                           const float* __restrict__ biasP,
                                           const half8 (&aIn)[4][7], half8 (&aOut)[4][7],
                                           f16* scr, const int lane,
                                           const int col16, const int g4)
{
#pragma unroll
    for (int p = 0; p < 7; ++p) {
        const int NT = (p < 6) ? 2 : 1;
        const float bv0 = biasP[(2 * p) * 16 + col16];
        const float bv1 = (NT == 2) ? biasP[(2 * p + 1) * 16 + col16] : 0.0f;
        floatx4 acc[4][2];
#pragma unroll
        for (int mt = 0; mt < 4; ++mt) {
            floatx4 v0; v0[0] = bv0; v0[1] = bv0; v0[2] = bv0; v0[3] = bv0;
            acc[mt][0] = v0;
            floatx4 v1; v1[0] = bv1; v1[1] = bv1; v1[2] = bv1; v1[3] = bv1;
            acc[mt][1] = v1;
        }
#pragma unroll
        for (int ks = 0; ks < NKS; ++ks) {
            const half8 bf0 = *(const half8*)&Wp[((size_t)(ks * 13 + 2 * p) * 64 + lane) * 8];
            half8 bf1;
            if (NT == 2) bf1 = *(const half8*)&Wp[((size_t)(ks * 13 + 2 * p + 1) * 64 + lane) * 8];
#pragma unroll
            for (int mt = 0; mt < 4; ++mt) {
                acc[mt][0] = __builtin_amdgcn_mfma_f32_16x16x32_f16(aIn[mt][ks], bf0, acc[mt][0], 0, 0, 0);
                if (NT == 2)
                    acc[mt][1] = __builtin_amdgcn_mfma_f32_16x16x32_f16(aIn[mt][ks], bf1, acc[mt][1], 0, 0, 0);
            }
        }
        // epilogue: relu + f16, write C tiles into scratch (cols 32p..32p+31)
#pragma unroll
        for (int mt = 0; mt < 4; ++mt) {
#pragma unroll
            for (int r = 0; r < 4; ++r) {
                const int row = mt * 16 + g4 * 4 + r;
                scr[row * SCR_W + col16]      = (f16)fmaxf(acc[mt][0][r], 0.0f);
                if (NT == 2)
                    scr[row * SCR_W + 16 + col16] = (f16)fmaxf(acc[mt][1][r], 0.0f);
                else
                    scr[row * SCR_W + 16 + col16] = (f16)0.0f;   // zero-pad cols 208..223
            }
        }
        // read back as next-layer A-frags for k-slot p (compiler inserts lgkmcnt)
#pragma unroll
        for (int mt = 0; mt < 4; ++mt)
            aOut[mt][p] = *(const half8*)&scr[(mt * 16 + col16) * SCR_W + g4 * 8];
    }
}

// ---------------------------------------------------------------------------
// Slab kernel: 4 waves x 64 rows; head -> L1 -> L2 -> L3 -> L4; no barriers.
// ---------------------------------------------------------------------------
__global__ __launch_bounds__(256, 1)
void mlp_slab(const float* __restrict__ x,
              const float* __restrict__ W0, const float* __restrict__ b0,
              const float* __restrict__ b4,
              const char* __restrict__ ws,
              float* __restrict__ out, int B)
{
    __shared__ f16 scrAll[4][64 * SCR_W];          // 20480 B
    const int tid   = threadIdx.x;
    const int lane  = tid & 63;
    const int w     = __builtin_amdgcn_readfirstlane(tid >> 6);
    const int col16 = lane & 15;
    const int g4    = lane >> 4;
    f16* scr = &scrAll[w][0];

    const float* Qi  = (const float*)(ws + WS_QI);
    const float* b1p = (const float*)(ws + WS_B1P);
    const float* b2p = (const float*)(ws + WS_B2P);
    const float* b3p = (const float*)(ws + WS_B3P);
    const f16*  Wp1  = (const f16*)(ws + WS_WP1);
    const f16*  Wp2  = (const f16*)(ws + WS_WP2);
    const f16*  Wp3  = (const f16*)(ws + WS_WP3);
    const f16*  Wp4  = (const f16*)(ws + WS_WP4);

    // ---- head: fc0 + reduced-KKT QP (fp32), lane l owns row blk*256+w*64+l ----
    const long g0 = (long)blockIdx.x * M_BLK + w * 64 + lane;
    float xr[NF];
    if (g0 < B) {
        const float4* xp = (const float4*)(x + g0 * NF);
        const float4 A = xp[0], Bv = xp[1];
        xr[0] = A.x; xr[1] = A.y; xr[2] = A.z; xr[3] = A.w;
        xr[4] = Bv.x; xr[5] = Bv.y; xr[6] = Bv.z; xr[7] = Bv.w;
    } else {
#pragma unroll
        for (int i = 0; i < NF; ++i) xr[i] = 0.0f;
    }
    float h[NF];
#pragma unroll
    for (int j = 0; j < NF; ++j) {
        float acc = b0[j];
#pragma unroll
        for (int k = 0; k < NF; ++k) acc = fmaf(W0[j * NF + k], xr[k], acc);
        h[j] = acc;
    }
    // z = Qi h - Qi A' nu, nu = (A Qi A')^-1 (A Qi h - A h); exact z = h for Q = I
    float tq[NF], u0[NF], u1[NF];
    const float h3 = h[3];
#pragma unroll
    for (int i = 0; i < NF; ++i) {
        float s = 0.0f;
#pragma unroll
        for (int k = 0; k < NF; ++k) s = fmaf(Qi[i * NF + k], h[k], s);
        tq[i] = s;
        u0[i] = fmaf(Qi[i * NF + 4], h3, Qi[i * NF + 5]);
        u1[i] = fmaf(Qi[i * NF + 6], h3, Qi[i * NF + 7]);
    }
    const float m00 = fmaf(h3, u0[4], u0[5]);
    const float m01 = fmaf(h3, u1[4], u1[5]);
    const float m10 = fmaf(h3, u0[6], u0[7]);
    const float m11 = fmaf(h3, u1[6], u1[7]);
    const float r0  = fmaf(h3, tq[4], tq[5]) - fmaf(h3, h[4], h[5]);
    const float r1  = fmaf(h3, tq[6], tq[7]) - fmaf(h3, h[6], h[7]);
    const float idet = 1.0f / (m00 * m11 - m01 * m10);
    const float nu0 = (m11 * r0 - m01 * r1) * idet;
    const float nu1 = (m00 * r1 - m10 * r0) * idet;

    {
        half8 zh, zz = {};
#pragma unroll
        for (int k = 0; k < 8; ++k) zh[k] = (f16)(tq[k] - u0[k] * nu0 - u1[k] * nu1);
        // scratch row = lane; z in cols 0..7, zeros 8..31 (k-pad for L1)
        *(half8*)&scr[lane * SCR_W + 0]  = zh;
        *(half8*)&scr[lane * SCR_W + 8]  = zz;
        *(half8*)&scr[lane * SCR_W + 16] = zz;
        *(half8*)&scr[lane * SCR_W + 24] = zz;
    }

    half8 aA[4][7], aB[4][7];
#pragma unroll
    for (int mt = 0; mt < 4; ++mt)
        aA[mt][0] = *(const half8*)&scr[(mt * 16 + col16) * SCR_W + g4 * 8];

    layer_slab<1>(Wp1, b1p, aA, aB, scr, lane, col16, g4);   // L1: 8 -> 208
    layer_slab<7>(Wp2, b2p, aB, aA, scr, lane, col16, g4);   // L2: 224 -> 208
    layer_slab<7>(Wp3, b3p, aA, aB, scr, lane, col16, g4);   // L3: 224 -> 208

    // ---- L4: 200 -> 8 ----
    {
        const float bias4 = b4[col16 & 7];
        floatx4 acc4[4];
#pragma unroll
        for (int mt = 0; mt < 4; ++mt) { floatx4 z_ = {}; acc4[mt] = z_; }
#pragma unroll
        for (int ks = 0; ks < 7; ++ks) {
            const half8 bf = *(const half8*)&Wp4[((size_t)ks * 64 + lane) * 8];
#pragma unroll
            for (int mt = 0; mt < 4; ++mt)
                acc4[mt] = __builtin_amdgcn_mfma_f32_16x16x32_f16(aB[mt][ks], bf, acc4[mt], 0, 0, 0);
        }
        const long rowbase = (long)blockIdx.x * M_BLK + w * 64;
#pragma unroll
        for (int mt = 0; mt < 4; ++mt) {
#pragma unroll
            for (int r = 0; r < 4; ++r) {
                const long g = rowbase + mt * 16 + g4 * 4 + r;
                if (col16 < NC && g < B) out[g * NC + col16] = acc4[mt][r] + bias4;
            }
        }
    }
}

// ===========================================================================
// Fallback fp32 path if ws_size is too small for prep data.
// ===========================================================================
#define BT 64
#define NWAVE 8
#define JB 25
#define CH 8

__device__ __forceinline__ void layer200(const float* __restrict__ in_,
                                         float* __restrict__ out_,
                                         const float* __restrict__ W,
                                         const float* __restrict__ bias,
                                         int j0, int lane)
{
    float acc[JB];
#pragma unroll
    for (int jj = 0; jj < JB; ++jj) acc[jj] = bias[j0 + jj];
#pragma unroll 1
    for (int k0 = 0; k0 < NH; k0 += CH) {
        float a[CH];
#pragma unroll
        for (int u = 0; u < CH; ++u) a[u] = in_[(k0 + u) * BT + lane];
#pragma unroll
        for (int jj = 0; jj < JB; ++jj) {
            const float* wr = W + (j0 + jj) * NH + k0;
#pragma unroll
            for (int u = 0; u < CH; ++u) acc[jj] = fmaf(wr[u], a[u], acc[jj]);
        }
    }
#pragma unroll
    for (int jj = 0; jj < JB; ++jj)
        out_[(j0 + jj) * BT + lane] = fmaxf(acc[jj], 0.0f);
}

__global__ void qinv_kernel(const float* __restrict__ Q, float* __restrict__ Qi)
{
    __shared__ float aug[8][16];
    __shared__ int piv;
    const int t  = threadIdx.x;
    const int r  = t >> 4;
    const int c2 = t & 15;
    aug[r][c2] = (c2 < 8) ? Q[r * 8 + c2] : ((c2 - 8 == r) ? 1.0f : 0.0f);
    __syncthreads();
    for (int c = 0; c < 8; ++c) {
        if (t == 0) {
            int p = c; float best = fabsf(aug[c][c]);
            for (int rr = c + 1; rr < 8; ++rr) {
                float v = fabsf(aug[rr][c]);
                if (v > best) { best = v; p = rr; }
            }
            piv = p;
        }
        __syncthreads();
        const int p = piv;
        float myv = aug[r][c2];
        __syncthreads();
        if (r == c)      aug[p][c2] = myv;
        else if (r == p) aug[c][c2] = myv;
        __syncthreads();
        const float pv = aug[c][c];
        __syncthreads();
        if (r == c) aug[r][c2] = aug[r][c2] / pv;
        __syncthreads();
        const float fac  = (r == c) ? 0.0f : aug[r][c];
        const float prow = aug[c][c2];
        __syncthreads();
        aug[r][c2] -= fac * prow;
        __syncthreads();
    }
    if (c2 >= 8) Qi[r * 8 + (c2 - 8)] = aug[r][c2];
}

__global__ __launch_bounds__(BT * NWAVE, 2)
void mlp_fused(const float* __restrict__ x, const float* __restrict__ Qi,
               const float* __restrict__ W0, const float* __restrict__ b0,
               const float* __restrict__ W1, const float* __restrict__ b1,
               const float* __restrict__ W2, const float* __restrict__ b2,
               const float* __restrict__ W3, const float* __restrict__ b3,
               const float* __restrict__ W4, const float* __restrict__ b4,
               float* __restrict__ out, int B)
{
    __shared__ float actA[NH * BT];
    __shared__ float actB[NH * BT];
    __shared__ float outP[NWAVE * NC * BT];

    const int lane = threadIdx.x & 63;
    const int wid  = __builtin_amdgcn_readfirstlane((int)(threadIdx.x >> 6));
    const int g    = blockIdx.x * BT + lane;
    const int j0   = wid * JB;

    float xr[NF];
    if (g < B) {
        const float4* xp = reinterpret_cast<const float4*>(x + (size_t)g * NF);
        float4 x0 = xp[0], x1 = xp[1];
        xr[0] = x0.x; xr[1] = x0.y; xr[2] = x0.z; xr[3] = x0.w;
        xr[4] = x1.x; xr[5] = x1.y; xr[6] = x1.z; xr[7] = x1.w;
    } else {
#pragma unroll
        for (int i = 0; i < NF; ++i) xr[i] = 0.0f;
    }
    float h[NF];
#pragma unroll
    for (int j = 0; j < NF; ++j) {
        float acc = b0[j];
#pragma unroll
        for (int k = 0; k < NF; ++k) acc = fmaf(W0[j * NF + k], xr[k], acc);
        h[j] = acc;
    }
    float tq[NF], u0[NF], u1[NF];
    const float h3 = h[3];
#pragma unroll
    for (int i = 0; i < NF; ++i) {
        float s = 0.0f;
#pragma unroll
        for (int k = 0; k < NF; ++k) s = fmaf(Qi[i * NF + k], h[k], s);
        tq[i] = s;
        u0[i] = fmaf(Qi[i * NF + 4], h3, Qi[i * NF + 5]);
        u1[i] = fmaf(Qi[i * NF + 6], h3, Qi[i * NF + 7]);
    }
    const float m00 = fmaf(h3, u0[4], u0[5]);
    const float m01 = fmaf(h3, u1[4], u1[5]);
    const float m10 = fmaf(h3, u0[6], u0[7]);
    const float m11 = fmaf(h3, u1[6], u1[7]);
    const float r0  = fmaf(h3, tq[4], tq[5]) - fmaf(h3, h[4], h[5]);
    const float r1  = fmaf(h3, tq[6], tq[7]) - fmaf(h3, h[6], h[7]);
    const float idet = 1.0f / (m00 * m11 - m01 * m10);
    const float nu0 = (m11 * r0 - m01 * r1) * idet;
    const float nu1 = (m00 * r1 - m10 * r0) * idet;
    float z[NF];
#pragma unroll
    for (int i = 0; i < NF; ++i) z[i] = tq[i] - u0[i] * nu0 - u1[i] * nu1;

#pragma unroll
    for (int jj = 0; jj < JB; ++jj) {
        const int j = j0 + jj;
        float acc = b1[j];
#pragma unroll
        for (int k = 0; k < NF; ++k) acc = fmaf(W1[j * NF + k], z[k], acc);
        actA[j * BT + lane] = fmaxf(acc, 0.0f);
    }
    __syncthreads();
    layer200(actA, actB, W2, b2, j0, lane);
    __syncthreads();
    layer200(actB, actA, W3, b3, j0, lane);
    __syncthreads();
    {
        float a[JB];
#pragma unroll
        for (int kk = 0; kk < JB; ++kk) a[kk] = actA[(j0 + kk) * BT + lane];
        float acc[NC];
#pragma unroll
        for (int o = 0; o < NC; ++o) acc[o] = 0.0f;
#pragma unroll
        for (int o = 0; o < NC; ++o) {
            const float* wr = W4 + o * NH + j0;
#pragma unroll
            for (int kk = 0; kk < JB; ++kk) acc[o] = fmaf(wr[kk], a[kk], acc[o]);
        }
#pragma unroll
        for (int o = 0; o < NC; ++o) outP[(wid * NC + o) * BT + lane] = acc[o];
    }
    __syncthreads();
    {
        float s = b4[wid];
#pragma unroll
        for (int w = 0; w < NWAVE; ++w) s += outP[(w * NC + wid) * BT + lane];
        if (g < B) out[(size_t)g * NC + wid] = s;
    }
}

// ===========================================================================
extern "C" void kernel_launch(void* const* d_in, const int* in_sizes, int n_in,
                              void* d_out, int out_size, void* d_ws, size_t ws_size,
                              hipStream_t stream)
{
    const float* x  = (const float*)d_in[0];
    const float* Q  = (const float*)d_in[1];
    const float* W0 = (const float*)d_in[2];
    const float* b0 = (const float*)d_in[3];
    const float* W1 = (const float*)d_in[4];
    const float* b1 = (const float*)d_in[5];
    const float* W2 = (const float*)d_in[6];
    const float* b2 = (const float*)d_in[7];
    const float* W3 = (const float*)d_in[8];
    const float* b3 = (const float*)d_in[9];
    const float* W4 = (const float*)d_in[10];
    const float* b4 = (const float*)d_in[11];
    float* out = (float*)d_out;

    const int B = in_sizes[0] / NF;

    if (ws_size >= WS_NEED) {
        hipLaunchKernelGGL(prep_kernel, dim3(23), dim3(256), 0, stream,
                           Q, W1, b1, W2, b2, W3, b3, W4, (char*)d_ws);
        hipLaunchKernelGGL(mlp_slab, dim3((B + M_BLK - 1) / M_BLK), dim3(256), 0, stream,
                           x, W0, b0, b4, (const char*)d_ws, out, B);
    } else {
        float* Qi = (float*)d_ws;
        hipLaunchKernelGGL(qinv_kernel, dim3(1), dim3(128), 0, stream, Q, Qi);
        hipLaunchKernelGGL(mlp_fused, dim3((B + BT - 1) / BT), dim3(BT * NWAVE), 0, stream,
                           x, Qi, W0, b0, W1, b1, W2, b2, W3, b3, W4, b4, out, B);
    }
}